// Round 18
// baseline (159.535 us; speedup 1.0000x reference)
//
#include <hip/hip_runtime.h>
#include <math.h>

// Problem constants
#define B_ 4
#define S_ 2048
#define E_ 512
#define H_ 8
#define D_ 64

typedef short bf16x8 __attribute__((ext_vector_type(8)));
typedef float f32x4 __attribute__((ext_vector_type(4)));

__device__ inline short f2bf(float f) {  // fp32 -> bf16 bits, RNE
  union { float f; unsigned u; } v; v.f = f;
  unsigned r = v.u + 0x7FFF + ((v.u >> 16) & 1);
  return (short)(r >> 16);
}
__device__ inline short f2bf_fast(float f) {  // round-half-up (P matrix only)
  union { float f; unsigned u; } v; v.f = f;
  return (short)((v.u + 0x8000u) >> 16);
}
__device__ inline float bf2f(short s) {
  union { unsigned u; float f; } v; v.u = ((unsigned)(unsigned short)s) << 16;
  return v.f;
}
// raw v_exp_f32: 2^x in one instruction (verified correct r5-r17).
__device__ __forceinline__ float exp2_hw(float x) {
  float r; asm("v_exp_f32 %0, %1" : "=v"(r) : "v"(x)); return r;
}

// Async global->LDS, 16B per lane (GEMM staging only).
__device__ __forceinline__ void gload16(const short* g, short* l) {
  __builtin_amdgcn_global_load_lds(
      (__attribute__((address_space(1))) void*)g,
      (__attribute__((address_space(3))) void*)l, 16, 0, 0);
}

// ---------------------------------------------------------------------------
// fused fp32->bf16 convert for X, W_in, W_out + RoPE cos/sin table
// (2048 x 16 float2, 256 KB) built into the ob region — dead during
// gemm_qkv, overwritten later by flash/merge. Same sincosf/fr expressions
// as the old per-thread epilogue -> bit-identical numerics. (r16 WIN)
// ---------------------------------------------------------------------------
__global__ __launch_bounds__(256) void cvt_all(
    const float* __restrict__ x, const float* __restrict__ win,
    const float* __restrict__ wout, short* __restrict__ xb,
    short* __restrict__ winb, short* __restrict__ woutb,
    float* __restrict__ tab) {
  int bid = blockIdx.x;
  if (bid >= 5120) {                         // RoPE table: idx = s*16 + dd
    int idx = (bid - 5120) * 256 + threadIdx.x;   // [0, 32768)
    int s = idx >> 4, dd = idx & 15;
    float fr = exp2f((float)dd * -0.8304820237f); // theta^(-2dd/32)
    float sn, cs;
    sincosf((float)s * fr, &sn, &cs);
    ((float2*)tab)[idx] = make_float2(cs, sn);
    return;
  }
  const float* src; short* dst; int i;
  if (bid < 4096)      { src = x;    dst = xb;    i = bid * 256 + threadIdx.x; }
  else if (bid < 4864) { src = win;  dst = winb;  i = (bid - 4096) * 256 + threadIdx.x; }
  else                 { src = wout; dst = woutb; i = (bid - 4864) * 256 + threadIdx.x; }
  float4 f = ((const float4*)src)[i];
  short4 o;
  o.x = f2bf(f.x); o.y = f2bf(f.y); o.z = f2bf(f.z); o.w = f2bf(f.w);
  ((short4*)dst)[i] = o;
}

// ---------------------------------------------------------------------------
// MFMA GEMM qkv (FROZEN: r4 structure + r15 setprio + r16 table-RoPE):
// 128x64 tile, BK=32, 4 waves, async global_load_lds staging, LDS dbuf,
// ONE barrier/K-step, 1536 blocks = 6/CU. Epilogue RoPE via L2-resident
// float2 table. q,k [bh][s][d]; V TRANSPOSED [bh][d][s].
// ---------------------------------------------------------------------------
__global__ __launch_bounds__(256, 6) void gemm_qkv_mfma(
    const short* __restrict__ Xb,    // [8192][512] bf16
    const short* __restrict__ Wb,    // [1536][512] bf16
    const float* __restrict__ tab,   // [2048][16] float2 cos/sin
    short* __restrict__ qb, short* __restrict__ kb, short* __restrict__ vbT) {
  __shared__ __align__(16) short As[2 * 128 * 32];   // 16 KB
  __shared__ __align__(16) short Bs[2 * 64 * 32];    //  8 KB
  const int tid = threadIdx.x;
  const int w = tid >> 6, lane = tid & 63;
  const int l15 = lane & 15, quad = lane >> 4;
  const int wm = w & 1, wn = w >> 1;
  const int m0 = blockIdx.x * 128;
  const int n0 = blockIdx.y * 64;

  const int srow = tid >> 2, sch = (tid & 3) * 8;
  const short* gA0 = Xb + (size_t)(m0 + srow) * E_ + sch;
  const short* gA1 = Xb + (size_t)(m0 + srow + 64) * E_ + sch;
  const short* gB0 = Wb + (size_t)(n0 + srow) * E_ + sch;

  f32x4 acc[4][2];
  for (int mt = 0; mt < 4; ++mt)
    for (int nt = 0; nt < 2; ++nt) acc[mt][nt] = (f32x4){0.f, 0.f, 0.f, 0.f};

  gload16(gA0, &As[tid * 8]);
  gload16(gA1, &As[2048 + tid * 8]);
  gload16(gB0, &Bs[tid * 8]);
  gA0 += 32; gA1 += 32; gB0 += 32;
  __syncthreads();

  int cur = 0;
  for (int t = 0; t < 16; ++t) {
    if (t < 15) {
      const int nbA = (cur ^ 1) * 4096, nbB = (cur ^ 1) * 2048;
      gload16(gA0, &As[nbA + tid * 8]);
      gload16(gA1, &As[nbA + 2048 + tid * 8]);
      gload16(gB0, &Bs[nbB + tid * 8]);
      gA0 += 32; gA1 += 32; gB0 += 32;
    }
    const int cbA = cur * 4096, cbB = cur * 2048;
    bf16x8 a[4], bfr[2];
#pragma unroll
    for (int mt = 0; mt < 4; ++mt)
      a[mt] = *(const bf16x8*)&As[cbA + (wm * 64 + mt * 16 + l15) * 32 + quad * 8];
#pragma unroll
    for (int nt = 0; nt < 2; ++nt)
      bfr[nt] = *(const bf16x8*)&Bs[cbB + (wn * 32 + nt * 16 + l15) * 32 + quad * 8];
    __builtin_amdgcn_s_setprio(1);           // T5 (r15, neutral-kept)
#pragma unroll
    for (int mt = 0; mt < 4; ++mt)
#pragma unroll
      for (int nt = 0; nt < 2; ++nt)
        acc[mt][nt] = __builtin_amdgcn_mfma_f32_16x16x32_bf16(a[mt], bfr[nt], acc[mt][nt], 0, 0, 0);
    __builtin_amdgcn_s_setprio(0);
    __syncthreads();
    cur ^= 1;
  }

  const int t3 = n0 >> 9;                // uniform per block: 0=q 1=k 2=v
  for (int nt = 0; nt < 2; ++nt) {
    const int n = n0 + wn * 32 + nt * 16 + l15;
    const int h = (n >> 6) & 7;
    const int d = n & 63;
    const bool dorope = (t3 < 2) && (d < 32);
    const float sgn = (d & 1) ? 1.f : -1.f;
    const int dd = d >> 1;                 // valid only under dorope
    for (int mt = 0; mt < 4; ++mt) {
      for (int i = 0; i < 4; ++i) {
        const int m = m0 + wm * 64 + mt * 16 + quad * 4 + i;
        const int b = m >> 11, s = m & (S_ - 1);
        float val = acc[mt][nt][i];
        float pv = __shfl_xor(val, 1, 64);
        float outv = val;
        if (dorope) {
          float2 cs = ((const float2*)tab)[(s << 4) | dd];
          outv = val * cs.x + pv * sgn * cs.y;
        }
        if (t3 == 2)
          vbT[((size_t)(b * 8 + h) * D_ + d) * S_ + s] = f2bf(outv);
        else {
          short* dst = (t3 == 0) ? qb : kb;
          dst[(((size_t)(b * 8 + h)) * S_ + s) * D_ + d] = f2bf(outv);
        }
      }
    }
  }
}

// ---------------------------------------------------------------------------
// gemm_out (FROZEN: r14 BK=64 structure + r15 setprio). 2 blocks/CU grid-
// capped; 8 iters x 8 barriers, 32 MFMA/barrier, two conflict-free [*][32]
// sub-tiles, LDS 48 KB (free at this residency).
// ---------------------------------------------------------------------------
__global__ __launch_bounds__(256) void gemm_out_mfma(
    const short* __restrict__ Ab, const short* __restrict__ Wb,
    float* __restrict__ out) {
  __shared__ __align__(16) short As[2 * 2 * 128 * 32];   // 32 KB
  __shared__ __align__(16) short Bs[2 * 2 * 64 * 32];    // 16 KB
  const int tid = threadIdx.x;
  const int w = tid >> 6, lane = tid & 63;
  const int l15 = lane & 15, quad = lane >> 4;
  const int wm = w & 1, wn = w >> 1;
  const int m0 = blockIdx.x * 128;
  const int n0 = blockIdx.y * 64;

  const int srow = tid >> 2, sch = (tid & 3) * 8;
  const short* gA0 = Ab + (size_t)(m0 + srow) * E_ + sch;        // rows 0-63
  const short* gA1 = Ab + (size_t)(m0 + srow + 64) * E_ + sch;   // rows 64-127
  const short* gB0 = Wb + (size_t)(n0 + srow) * E_ + sch;        // rows 0-63

  f32x4 acc[4][2];
  for (int mt = 0; mt < 4; ++mt)
    for (int nt = 0; nt < 2; ++nt) acc[mt][nt] = (f32x4){0.f, 0.f, 0.f, 0.f};

#define STAGE_OUT(buf, koff)                                         \
  {                                                                  \
    const int ab = (buf) * 8192, bb = (buf) * 4096;                  \
    gload16(gA0 + (koff),      &As[ab + tid * 8]);                   \
    gload16(gA1 + (koff),      &As[ab + 2048 + tid * 8]);            \
    gload16(gA0 + (koff) + 32, &As[ab + 4096 + tid * 8]);            \
    gload16(gA1 + (koff) + 32, &As[ab + 4096 + 2048 + tid * 8]);     \
    gload16(gB0 + (koff),      &Bs[bb + tid * 8]);                   \
    gload16(gB0 + (koff) + 32, &Bs[bb + 2048 + tid * 8]);            \
  }

  STAGE_OUT(0, 0);
  __syncthreads();

  int cur = 0;
  for (int t = 0; t < 8; ++t) {
    if (t < 7) STAGE_OUT(cur ^ 1, (t + 1) * 64);
    const int cbA = cur * 8192, cbB = cur * 4096;
#pragma unroll
    for (int s = 0; s < 2; ++s) {
      bf16x8 a[4], bfr[2];
#pragma unroll
      for (int mt = 0; mt < 4; ++mt)
        a[mt] = *(const bf16x8*)&As[cbA + s * 4096 + (wm * 64 + mt * 16 + l15) * 32 + quad * 8];
#pragma unroll
      for (int nt = 0; nt < 2; ++nt)
        bfr[nt] = *(const bf16x8*)&Bs[cbB + s * 2048 + (wn * 32 + nt * 16 + l15) * 32 + quad * 8];
      __builtin_amdgcn_s_setprio(1);
#pragma unroll
      for (int mt = 0; mt < 4; ++mt)
#pragma unroll
        for (int nt = 0; nt < 2; ++nt)
          acc[mt][nt] = __builtin_amdgcn_mfma_f32_16x16x32_bf16(a[mt], bfr[nt], acc[mt][nt], 0, 0, 0);
      __builtin_amdgcn_s_setprio(0);
    }
    __syncthreads();
    cur ^= 1;
  }
#undef STAGE_OUT
  for (int mt = 0; mt < 4; ++mt)
    for (int nt = 0; nt < 2; ++nt) {
      const int n = n0 + wn * 32 + nt * 16 + l15;
      for (int i = 0; i < 4; ++i) {
        const int m = m0 + wm * 64 + mt * 16 + quad * 4 + i;
        out[(size_t)m * E_ + n] = acc[mt][nt][i];
      }
    }
}

// ---------------------------------------------------------------------------
// Flash attention (FROZEN at r13 = r6 structure + T5 setprio; band
// 46.1-48.8 across identical-binary runs). grid 1024 balanced pairs,
// stride 72, staged K/V loop, kbias LDS, 2 barriers/tile, exp2_hw, setprio
// around MFMA clusters. Refuted: stride-68 (+4), T14 (+7), grid-2048
// (+3.5), direct-global frags (2.6x). The path past ~47us is the full
// 8-warp 32x32 dep-graph rewrite — partial grafts all measured negative.
// ---------------------------------------------------------------------------
__global__ __launch_bounds__(256) void flash_mfma(
    const short* __restrict__ qb, const short* __restrict__ kb,
    const short* __restrict__ vbT, const int* __restrict__ maskp,
    short* __restrict__ pb0, short* __restrict__ pb1,
    float* __restrict__ lb0, float* __restrict__ lb1,
    short* __restrict__ ob) {
  __shared__ __align__(16) short Ks[64][72];
  __shared__ __align__(16) short VT[64][72];
  __shared__ __align__(16) short Pl[4][16][72];
  __shared__ float kbias[64];
  const int tid = threadIdx.x;
  const int w = tid >> 6, lane = tid & 63;
  const int l15 = lane & 15, quad = lane >> 4;
  const int bid = blockIdx.x;
  const int u = bid & 7, v = bid >> 3;       // u -> XCD under id&7 model
  const int bh = (u << 2) | (v & 3);         // 4 bh per XCD
  const int w2 = v >> 2;                     // 0..31
  const int pair = w2 & 15;                  // q-tile pair id
  const int kh = w2 >> 4;                    // split half: 0 or 1
  const int b = bh >> 3, hd = bh & 7;
  const short* qbase = qb + (size_t)bh * S_ * D_;
  const short* kbase = kb + (size_t)bh * S_ * D_;
  const short* vtb   = vbT + (size_t)bh * D_ * S_;
  short* PB = kh ? pb1 : pb0;
  float* LB = kh ? lb1 : lb0;
  const float c2 = 0.1803368801f;            // 0.125 * log2(e)
  bf16x8 ones;
  for (int j = 0; j < 8; ++j) ones[j] = (short)0x3F80;  // bf16 1.0

  for (int seg = 0; seg < 2; ++seg) {
    const int qt = (seg == 0) ? pair : 31 - pair;
    const int r0 = qt * 64;
    const int mid = (qt + 2) >> 1;           // ceil((qt+1)/2)
    const int lo = kh ? mid : 0;
    const int hi = kh ? (qt + 1) : mid;
    bf16x8 aq[2];
    {
      const short* qrow = qbase + (size_t)(r0 + 16 * w + l15) * D_;
      aq[0] = *(const bf16x8*)&qrow[quad * 8];
      aq[1] = *(const bf16x8*)&qrow[32 + quad * 8];
    }
    f32x4 o[4], lsum;
    for (int no = 0; no < 4; ++no) o[no] = (f32x4){0.f, 0.f, 0.f, 0.f};
    lsum = (f32x4){0.f, 0.f, 0.f, 0.f};

    for (int kt = lo; kt < hi; ++kt) {
      const int t0 = kt * 64;
      __syncthreads();                       // prior tile fully consumed
      for (int l = 0; l < 2; ++l) {
        int idx = tid + 256 * l;
        int row = idx >> 3, ch = (idx & 7) * 8;
        *(bf16x8*)&Ks[row][ch] = *(const bf16x8*)(kbase + (size_t)(t0 + row) * D_ + ch);
        *(bf16x8*)&VT[row][ch] = *(const bf16x8*)(vtb + (size_t)row * S_ + t0 + ch);
      }
      if (tid < 64)
        kbias[tid] = maskp[b * S_ + t0 + tid] ? -23.08312f : -1.0e38f;
      __syncthreads();
      f32x4 sfr[4];
      for (int nb = 0; nb < 4; ++nb) sfr[nb] = (f32x4){0.f, 0.f, 0.f, 0.f};
      __builtin_amdgcn_s_setprio(1);         // T5: favor MFMA cluster
      for (int nb = 0; nb < 4; ++nb)
        for (int ks = 0; ks < 2; ++ks) {
          bf16x8 bk = *(const bf16x8*)&Ks[l15 + 16 * nb][32 * ks + quad * 8];
          sfr[nb] = __builtin_amdgcn_mfma_f32_16x16x32_bf16(aq[ks], bk, sfr[nb], 0, 0, 0);
        }
      __builtin_amdgcn_s_setprio(0);
      if (kt < qt) {                         // interior tiles: no causal test
        for (int nb = 0; nb < 4; ++nb) {
          const float bb = kbias[l15 + 16 * nb];
          for (int i = 0; i < 4; ++i)
            Pl[w][quad * 4 + i][l15 + 16 * nb] = f2bf_fast(exp2_hw(sfr[nb][i] * c2 + bb));
        }
      } else {                               // boundary tile: add causal mask
        for (int nb = 0; nb < 4; ++nb) {
          const int tg = l15 + 16 * nb;
          const float bb = kbias[l15 + 16 * nb];
          for (int i = 0; i < 4; ++i) {
            const float bbi = (tg > 16 * w + quad * 4 + i) ? -1.0e38f : bb;
            Pl[w][quad * 4 + i][l15 + 16 * nb] = f2bf_fast(exp2_hw(sfr[nb][i] * c2 + bbi));
          }
        }
      }
      asm volatile("s_waitcnt lgkmcnt(0)" ::: "memory");  // own-wave Pl writes
      bf16x8 ap0 = *(const bf16x8*)&Pl[w][l15][quad * 8];
      bf16x8 ap1 = *(const bf16x8*)&Pl[w][l15][32 + quad * 8];
      __builtin_amdgcn_s_setprio(1);         // T5: favor PV cluster
      for (int no = 0; no < 4; ++no) {
        bf16x8 bv0 = *(const bf16x8*)&VT[16 * no + l15][quad * 8];
        bf16x8 bv1 = *(const bf16x8*)&VT[16 * no + l15][32 + quad * 8];
        o[no] = __builtin_amdgcn_mfma_f32_16x16x32_bf16(ap0, bv0, o[no], 0, 0, 0);
        o[no] = __builtin_amdgcn_mfma_f32_16x16x32_bf16(ap1, bv1, o[no], 0, 0, 0);
      }
      lsum = __builtin_amdgcn_mfma_f32_16x16x32_bf16(ap0, ones, lsum, 0, 0, 0);
      lsum = __builtin_amdgcn_mfma_f32_16x16x32_bf16(ap1, ones, lsum, 0, 0, 0);
      __builtin_amdgcn_s_setprio(0);
    }
    // epilogue: write partials; kh=0 also writes V rows for masked queries
    for (int i = 0; i < 4; ++i) {
      const int s = r0 + 16 * w + quad * 4 + i;
      const int qm = maskp[b * S_ + s];
      const size_t row = (size_t)(b * S_ + s) * E_ + hd * D_;
      if (kh == 0 && !qm) {
        for (int no = 0; no < 4; ++no) {
          const int d = l15 + 16 * no;
          ob[row + d] = vtb[(size_t)d * S_ + s];
        }
      }
      for (int no = 0; no < 4; ++no)
        PB[row + l15 + 16 * no] = f2bf(o[no][i]);
      if (l15 == 0)
        LB[bh * S_ + s] = lsum[i];
    }
  }
}

// ---------------------------------------------------------------------------
// merge: ob[m][e] = (P0 + P1) / (l0 + l1) for unmasked rows
// ---------------------------------------------------------------------------
__global__ __launch_bounds__(256) void merge_kernel(
    const short* __restrict__ pb0, const short* __restrict__ pb1,
    const float* __restrict__ lb0, const float* __restrict__ lb1,
    const int* __restrict__ maskp, short* __restrict__ ob) {
  int idx = blockIdx.x * 256 + threadIdx.x;  // 8192*64 threads
  int m = idx >> 6, e = (idx & 63) * 8;
  if (!maskp[m]) return;                     // masked row: flash wrote V
  int b = m >> 11, s = m & (S_ - 1);
  int bh = b * 8 + (e >> 6);
  float l = lb0[bh * S_ + s] + lb1[bh * S_ + s];
  float inv = 1.f / l;
  bf16x8 p0 = *(const bf16x8*)&pb0[(size_t)m * E_ + e];
  bf16x8 p1 = *(const bf16x8*)&pb1[(size_t)m * E_ + e];
  bf16x8 r;
  for (int j = 0; j < 8; ++j)
    r[j] = f2bf((bf2f(p0[j]) + bf2f(p1[j])) * inv);
  *(bf16x8*)&ob[(size_t)m * E_ + e] = r;
}

extern "C" void kernel_launch(void* const* d_in, const int* in_sizes, int n_in,
                              void* d_out, int out_size, void* d_ws, size_t ws_size,
                              hipStream_t stream) {
  const float* x    = (const float*)d_in[0];
  const int*   mask = (const int*)d_in[1];
  const float* Win  = (const float*)d_in[2];
  const float* Wout = (const float*)d_in[3];
  float* out = (float*)d_out;

  short* Xb    = (short*)d_ws;               // 8192*512
  short* Winb  = Xb + 8192 * 512;            // 1536*512
  short* Woutb = Winb + 1536 * 512;          // 512*512
  short* qb    = Woutb + 512 * 512;          // 32*2048*64 each
  short* kb    = qb + 32 * 2048 * 64;
  short* vbT   = kb + 32 * 2048 * 64;        // [bh][d][s] transposed
  short* ob    = vbT + 32 * 2048 * 64;       // 8192*512
  short* pb0   = ob + 8192 * 512;            // partial O, half 0 (bf16)
  short* pb1   = pb0 + 8192 * 512;           // partial O, half 1
  float* lb0   = (float*)(pb1 + 8192 * 512); // lsum partials [32][2048]
  float* lb1   = lb0 + 32 * 2048;            // total ws ~61.3 MB
  float* tab   = (float*)ob;                 // RoPE table (256KB) in ob
                                             // region — dead until flash

  cvt_all<<<5248, 256, 0, stream>>>(x, Win, Wout, Xb, Winb, Woutb, tab);
  gemm_qkv_mfma<<<dim3(64, 24), 256, 0, stream>>>(Xb, Winb, tab, qb, kb, vbT);
  flash_mfma<<<1024, 256, 0, stream>>>(qb, kb, vbT, mask, pb0, pb1, lb0, lb1, ob);
  merge_kernel<<<2048, 256, 0, stream>>>(pb0, pb1, lb0, lb1, mask, ob);
  gemm_out_mfma<<<dim3(64, 8), 256, 0, stream>>>(ob, Woutb, out);
}

// Round 19
// 158.358 us; speedup vs baseline: 1.0074x; 1.0074x over previous
//
#include <hip/hip_runtime.h>
#include <math.h>

// Problem constants
#define B_ 4
#define S_ 2048
#define E_ 512
#define H_ 8
#define D_ 64

typedef short bf16x8 __attribute__((ext_vector_type(8)));
typedef float f32x4 __attribute__((ext_vector_type(4)));

__device__ inline short f2bf(float f) {  // fp32 -> bf16 bits, RNE
  union { float f; unsigned u; } v; v.f = f;
  unsigned r = v.u + 0x7FFF + ((v.u >> 16) & 1);
  return (short)(r >> 16);
}
__device__ inline short f2bf_fast(float f) {  // round-half-up (P matrix only)
  union { float f; unsigned u; } v; v.f = f;
  return (short)((v.u + 0x8000u) >> 16);
}
__device__ inline float bf2f(short s) {
  union { unsigned u; float f; } v; v.u = ((unsigned)(unsigned short)s) << 16;
  return v.f;
}
// raw v_exp_f32: 2^x in one instruction (verified correct r5-r18).
__device__ __forceinline__ float exp2_hw(float x) {
  float r; asm("v_exp_f32 %0, %1" : "=v"(r) : "v"(x)); return r;
}

// Async global->LDS, 16B per lane (GEMM staging only).
__device__ __forceinline__ void gload16(const short* g, short* l) {
  __builtin_amdgcn_global_load_lds(
      (__attribute__((address_space(1))) void*)g,
      (__attribute__((address_space(3))) void*)l, 16, 0, 0);
}

// ---------------------------------------------------------------------------
// fused fp32->bf16 convert for X, W_in, W_out + RoPE cos/sin table
// (2048 x 16 float2, 256 KB) built into the ob region — dead during
// gemm_qkv, overwritten later by flash/merge. (r16 WIN: -1.3us)
// ---------------------------------------------------------------------------
__global__ __launch_bounds__(256) void cvt_all(
    const float* __restrict__ x, const float* __restrict__ win,
    const float* __restrict__ wout, short* __restrict__ xb,
    short* __restrict__ winb, short* __restrict__ woutb,
    float* __restrict__ tab) {
  int bid = blockIdx.x;
  if (bid >= 5120) {                         // RoPE table: idx = s*16 + dd
    int idx = (bid - 5120) * 256 + threadIdx.x;   // [0, 32768)
    int s = idx >> 4, dd = idx & 15;
    float fr = exp2f((float)dd * -0.8304820237f); // theta^(-2dd/32)
    float sn, cs;
    sincosf((float)s * fr, &sn, &cs);
    ((float2*)tab)[idx] = make_float2(cs, sn);
    return;
  }
  const float* src; short* dst; int i;
  if (bid < 4096)      { src = x;    dst = xb;    i = bid * 256 + threadIdx.x; }
  else if (bid < 4864) { src = win;  dst = winb;  i = (bid - 4096) * 256 + threadIdx.x; }
  else                 { src = wout; dst = woutb; i = (bid - 4864) * 256 + threadIdx.x; }
  float4 f = ((const float4*)src)[i];
  short4 o;
  o.x = f2bf(f.x); o.y = f2bf(f.y); o.z = f2bf(f.z); o.w = f2bf(f.w);
  ((short4*)dst)[i] = o;
}

// ---------------------------------------------------------------------------
// MFMA GEMM qkv (FROZEN: r4 structure + r15 setprio + r16 table-RoPE):
// 128x64 tile, BK=32, 4 waves, async global_load_lds staging, LDS dbuf,
// ONE barrier/K-step, 1536 blocks = 6/CU. Epilogue RoPE via L2-resident
// float2 table. q,k [bh][s][d]; V TRANSPOSED [bh][d][s]. A-panel reuse is
// already XCD-local (blocks sharing m0 have bid ≡ x mod 8) — T1 n/a.
// ---------------------------------------------------------------------------
__global__ __launch_bounds__(256, 6) void gemm_qkv_mfma(
    const short* __restrict__ Xb,    // [8192][512] bf16
    const short* __restrict__ Wb,    // [1536][512] bf16
    const float* __restrict__ tab,   // [2048][16] float2 cos/sin
    short* __restrict__ qb, short* __restrict__ kb, short* __restrict__ vbT) {
  __shared__ __align__(16) short As[2 * 128 * 32];   // 16 KB
  __shared__ __align__(16) short Bs[2 * 64 * 32];    //  8 KB
  const int tid = threadIdx.x;
  const int w = tid >> 6, lane = tid & 63;
  const int l15 = lane & 15, quad = lane >> 4;
  const int wm = w & 1, wn = w >> 1;
  const int m0 = blockIdx.x * 128;
  const int n0 = blockIdx.y * 64;

  const int srow = tid >> 2, sch = (tid & 3) * 8;
  const short* gA0 = Xb + (size_t)(m0 + srow) * E_ + sch;
  const short* gA1 = Xb + (size_t)(m0 + srow + 64) * E_ + sch;
  const short* gB0 = Wb + (size_t)(n0 + srow) * E_ + sch;

  f32x4 acc[4][2];
  for (int mt = 0; mt < 4; ++mt)
    for (int nt = 0; nt < 2; ++nt) acc[mt][nt] = (f32x4){0.f, 0.f, 0.f, 0.f};

  gload16(gA0, &As[tid * 8]);
  gload16(gA1, &As[2048 + tid * 8]);
  gload16(gB0, &Bs[tid * 8]);
  gA0 += 32; gA1 += 32; gB0 += 32;
  __syncthreads();

  int cur = 0;
  for (int t = 0; t < 16; ++t) {
    if (t < 15) {
      const int nbA = (cur ^ 1) * 4096, nbB = (cur ^ 1) * 2048;
      gload16(gA0, &As[nbA + tid * 8]);
      gload16(gA1, &As[nbA + 2048 + tid * 8]);
      gload16(gB0, &Bs[nbB + tid * 8]);
      gA0 += 32; gA1 += 32; gB0 += 32;
    }
    const int cbA = cur * 4096, cbB = cur * 2048;
    bf16x8 a[4], bfr[2];
#pragma unroll
    for (int mt = 0; mt < 4; ++mt)
      a[mt] = *(const bf16x8*)&As[cbA + (wm * 64 + mt * 16 + l15) * 32 + quad * 8];
#pragma unroll
    for (int nt = 0; nt < 2; ++nt)
      bfr[nt] = *(const bf16x8*)&Bs[cbB + (wn * 32 + nt * 16 + l15) * 32 + quad * 8];
    __builtin_amdgcn_s_setprio(1);           // T5 (r15, neutral-kept)
#pragma unroll
    for (int mt = 0; mt < 4; ++mt)
#pragma unroll
      for (int nt = 0; nt < 2; ++nt)
        acc[mt][nt] = __builtin_amdgcn_mfma_f32_16x16x32_bf16(a[mt], bfr[nt], acc[mt][nt], 0, 0, 0);
    __builtin_amdgcn_s_setprio(0);
    __syncthreads();
    cur ^= 1;
  }

  const int t3 = n0 >> 9;                // uniform per block: 0=q 1=k 2=v
  for (int nt = 0; nt < 2; ++nt) {
    const int n = n0 + wn * 32 + nt * 16 + l15;
    const int h = (n >> 6) & 7;
    const int d = n & 63;
    const bool dorope = (t3 < 2) && (d < 32);
    const float sgn = (d & 1) ? 1.f : -1.f;
    const int dd = d >> 1;                 // valid only under dorope
    for (int mt = 0; mt < 4; ++mt) {
      for (int i = 0; i < 4; ++i) {
        const int m = m0 + wm * 64 + mt * 16 + quad * 4 + i;
        const int b = m >> 11, s = m & (S_ - 1);
        float val = acc[mt][nt][i];
        float pv = __shfl_xor(val, 1, 64);
        float outv = val;
        if (dorope) {
          float2 cs = ((const float2*)tab)[(s << 4) | dd];
          outv = val * cs.x + pv * sgn * cs.y;
        }
        if (t3 == 2)
          vbT[((size_t)(b * 8 + h) * D_ + d) * S_ + s] = f2bf(outv);
        else {
          short* dst = (t3 == 0) ? qb : kb;
          dst[(((size_t)(b * 8 + h)) * S_ + s) * D_ + d] = f2bf(outv);
        }
      }
    }
  }
}

// ---------------------------------------------------------------------------
// gemm_out (FROZEN: r14 BK=64 structure + r15 setprio). 2 blocks/CU grid-
// capped; 8 iters x 8 barriers, 32 MFMA/barrier, two conflict-free [*][32]
// sub-tiles, LDS 48 KB (free at this residency).
// ---------------------------------------------------------------------------
__global__ __launch_bounds__(256) void gemm_out_mfma(
    const short* __restrict__ Ab, const short* __restrict__ Wb,
    float* __restrict__ out) {
  __shared__ __align__(16) short As[2 * 2 * 128 * 32];   // 32 KB
  __shared__ __align__(16) short Bs[2 * 2 * 64 * 32];    // 16 KB
  const int tid = threadIdx.x;
  const int w = tid >> 6, lane = tid & 63;
  const int l15 = lane & 15, quad = lane >> 4;
  const int wm = w & 1, wn = w >> 1;
  const int m0 = blockIdx.x * 128;
  const int n0 = blockIdx.y * 64;

  const int srow = tid >> 2, sch = (tid & 3) * 8;
  const short* gA0 = Ab + (size_t)(m0 + srow) * E_ + sch;        // rows 0-63
  const short* gA1 = Ab + (size_t)(m0 + srow + 64) * E_ + sch;   // rows 64-127
  const short* gB0 = Wb + (size_t)(n0 + srow) * E_ + sch;        // rows 0-63

  f32x4 acc[4][2];
  for (int mt = 0; mt < 4; ++mt)
    for (int nt = 0; nt < 2; ++nt) acc[mt][nt] = (f32x4){0.f, 0.f, 0.f, 0.f};

#define STAGE_OUT(buf, koff)                                         \
  {                                                                  \
    const int ab = (buf) * 8192, bb = (buf) * 4096;                  \
    gload16(gA0 + (koff),      &As[ab + tid * 8]);                   \
    gload16(gA1 + (koff),      &As[ab + 2048 + tid * 8]);            \
    gload16(gA0 + (koff) + 32, &As[ab + 4096 + tid * 8]);            \
    gload16(gA1 + (koff) + 32, &As[ab + 4096 + 2048 + tid * 8]);     \
    gload16(gB0 + (koff),      &Bs[bb + tid * 8]);                   \
    gload16(gB0 + (koff) + 32, &Bs[bb + 2048 + tid * 8]);            \
  }

  STAGE_OUT(0, 0);
  __syncthreads();

  int cur = 0;
  for (int t = 0; t < 8; ++t) {
    if (t < 7) STAGE_OUT(cur ^ 1, (t + 1) * 64);
    const int cbA = cur * 8192, cbB = cur * 4096;
#pragma unroll
    for (int s = 0; s < 2; ++s) {
      bf16x8 a[4], bfr[2];
#pragma unroll
      for (int mt = 0; mt < 4; ++mt)
        a[mt] = *(const bf16x8*)&As[cbA + s * 4096 + (wm * 64 + mt * 16 + l15) * 32 + quad * 8];
#pragma unroll
      for (int nt = 0; nt < 2; ++nt)
        bfr[nt] = *(const bf16x8*)&Bs[cbB + s * 2048 + (wn * 32 + nt * 16 + l15) * 32 + quad * 8];
      __builtin_amdgcn_s_setprio(1);
#pragma unroll
      for (int mt = 0; mt < 4; ++mt)
#pragma unroll
        for (int nt = 0; nt < 2; ++nt)
          acc[mt][nt] = __builtin_amdgcn_mfma_f32_16x16x32_bf16(a[mt], bfr[nt], acc[mt][nt], 0, 0, 0);
      __builtin_amdgcn_s_setprio(0);
    }
    __syncthreads();
    cur ^= 1;
  }
#undef STAGE_OUT
  for (int mt = 0; mt < 4; ++mt)
    for (int nt = 0; nt < 2; ++nt) {
      const int n = n0 + wn * 32 + nt * 16 + l15;
      for (int i = 0; i < 4; ++i) {
        const int m = m0 + wm * 64 + mt * 16 + quad * 4 + i;
        out[(size_t)m * E_ + n] = acc[mt][nt][i];
      }
    }
}

// ---------------------------------------------------------------------------
// Flash attention (FROZEN at r13 = r6 structure + T5 setprio; band
// 46.1-48.8 across identical-binary runs). grid 1024 balanced pairs,
// stride 72, staged K/V loop, kbias LDS, 2 barriers/tile, exp2_hw, setprio
// around MFMA clusters. Refuted: stride-68 (+4), T14 (+7), grid-2048
// (+3.5), direct-global frags (2.6x). The path past ~47us is the full
// 8-warp 32x32 dep-graph rewrite — partial grafts all measured negative.
// ---------------------------------------------------------------------------
__global__ __launch_bounds__(256) void flash_mfma(
    const short* __restrict__ qb, const short* __restrict__ kb,
    const short* __restrict__ vbT, const int* __restrict__ maskp,
    short* __restrict__ pb0, short* __restrict__ pb1,
    float* __restrict__ lb0, float* __restrict__ lb1,
    short* __restrict__ ob) {
  __shared__ __align__(16) short Ks[64][72];
  __shared__ __align__(16) short VT[64][72];
  __shared__ __align__(16) short Pl[4][16][72];
  __shared__ float kbias[64];
  const int tid = threadIdx.x;
  const int w = tid >> 6, lane = tid & 63;
  const int l15 = lane & 15, quad = lane >> 4;
  const int bid = blockIdx.x;
  const int u = bid & 7, v = bid >> 3;       // u -> XCD under id&7 model
  const int bh = (u << 2) | (v & 3);         // 4 bh per XCD
  const int w2 = v >> 2;                     // 0..31
  const int pair = w2 & 15;                  // q-tile pair id
  const int kh = w2 >> 4;                    // split half: 0 or 1
  const int b = bh >> 3, hd = bh & 7;
  const short* qbase = qb + (size_t)bh * S_ * D_;
  const short* kbase = kb + (size_t)bh * S_ * D_;
  const short* vtb   = vbT + (size_t)bh * D_ * S_;
  short* PB = kh ? pb1 : pb0;
  float* LB = kh ? lb1 : lb0;
  const float c2 = 0.1803368801f;            // 0.125 * log2(e)
  bf16x8 ones;
  for (int j = 0; j < 8; ++j) ones[j] = (short)0x3F80;  // bf16 1.0

  for (int seg = 0; seg < 2; ++seg) {
    const int qt = (seg == 0) ? pair : 31 - pair;
    const int r0 = qt * 64;
    const int mid = (qt + 2) >> 1;           // ceil((qt+1)/2)
    const int lo = kh ? mid : 0;
    const int hi = kh ? (qt + 1) : mid;
    bf16x8 aq[2];
    {
      const short* qrow = qbase + (size_t)(r0 + 16 * w + l15) * D_;
      aq[0] = *(const bf16x8*)&qrow[quad * 8];
      aq[1] = *(const bf16x8*)&qrow[32 + quad * 8];
    }
    f32x4 o[4], lsum;
    for (int no = 0; no < 4; ++no) o[no] = (f32x4){0.f, 0.f, 0.f, 0.f};
    lsum = (f32x4){0.f, 0.f, 0.f, 0.f};

    for (int kt = lo; kt < hi; ++kt) {
      const int t0 = kt * 64;
      __syncthreads();                       // prior tile fully consumed
      for (int l = 0; l < 2; ++l) {
        int idx = tid + 256 * l;
        int row = idx >> 3, ch = (idx & 7) * 8;
        *(bf16x8*)&Ks[row][ch] = *(const bf16x8*)(kbase + (size_t)(t0 + row) * D_ + ch);
        *(bf16x8*)&VT[row][ch] = *(const bf16x8*)(vtb + (size_t)row * S_ + t0 + ch);
      }
      if (tid < 64)
        kbias[tid] = maskp[b * S_ + t0 + tid] ? -23.08312f : -1.0e38f;
      __syncthreads();
      f32x4 sfr[4];
      for (int nb = 0; nb < 4; ++nb) sfr[nb] = (f32x4){0.f, 0.f, 0.f, 0.f};
      __builtin_amdgcn_s_setprio(1);         // T5: favor MFMA cluster
      for (int nb = 0; nb < 4; ++nb)
        for (int ks = 0; ks < 2; ++ks) {
          bf16x8 bk = *(const bf16x8*)&Ks[l15 + 16 * nb][32 * ks + quad * 8];
          sfr[nb] = __builtin_amdgcn_mfma_f32_16x16x32_bf16(aq[ks], bk, sfr[nb], 0, 0, 0);
        }
      __builtin_amdgcn_s_setprio(0);
      if (kt < qt) {                         // interior tiles: no causal test
        for (int nb = 0; nb < 4; ++nb) {
          const float bb = kbias[l15 + 16 * nb];
          for (int i = 0; i < 4; ++i)
            Pl[w][quad * 4 + i][l15 + 16 * nb] = f2bf_fast(exp2_hw(sfr[nb][i] * c2 + bb));
        }
      } else {                               // boundary tile: add causal mask
        for (int nb = 0; nb < 4; ++nb) {
          const int tg = l15 + 16 * nb;
          const float bb = kbias[l15 + 16 * nb];
          for (int i = 0; i < 4; ++i) {
            const float bbi = (tg > 16 * w + quad * 4 + i) ? -1.0e38f : bb;
            Pl[w][quad * 4 + i][l15 + 16 * nb] = f2bf_fast(exp2_hw(sfr[nb][i] * c2 + bbi));
          }
        }
      }
      asm volatile("s_waitcnt lgkmcnt(0)" ::: "memory");  // own-wave Pl writes
      bf16x8 ap0 = *(const bf16x8*)&Pl[w][l15][quad * 8];
      bf16x8 ap1 = *(const bf16x8*)&Pl[w][l15][32 + quad * 8];
      __builtin_amdgcn_s_setprio(1);         // T5: favor PV cluster
      for (int no = 0; no < 4; ++no) {
        bf16x8 bv0 = *(const bf16x8*)&VT[16 * no + l15][quad * 8];
        bf16x8 bv1 = *(const bf16x8*)&VT[16 * no + l15][32 + quad * 8];
        o[no] = __builtin_amdgcn_mfma_f32_16x16x32_bf16(ap0, bv0, o[no], 0, 0, 0);
        o[no] = __builtin_amdgcn_mfma_f32_16x16x32_bf16(ap1, bv1, o[no], 0, 0, 0);
      }
      lsum = __builtin_amdgcn_mfma_f32_16x16x32_bf16(ap0, ones, lsum, 0, 0, 0);
      lsum = __builtin_amdgcn_mfma_f32_16x16x32_bf16(ap1, ones, lsum, 0, 0, 0);
      __builtin_amdgcn_s_setprio(0);
    }
    // epilogue: write partials; kh=0 also writes V rows for masked queries
    for (int i = 0; i < 4; ++i) {
      const int s = r0 + 16 * w + quad * 4 + i;
      const int qm = maskp[b * S_ + s];
      const size_t row = (size_t)(b * S_ + s) * E_ + hd * D_;
      if (kh == 0 && !qm) {
        for (int no = 0; no < 4; ++no) {
          const int d = l15 + 16 * no;
          ob[row + d] = vtb[(size_t)d * S_ + s];
        }
      }
      for (int no = 0; no < 4; ++no)
        PB[row + l15 + 16 * no] = f2bf(o[no][i]);
      if (l15 == 0)
        LB[bh * S_ + s] = lsum[i];
    }
  }
}

// ---------------------------------------------------------------------------
// merge: ob[m][e] = (P0 + P1) / (l0 + l1) for unmasked rows
// ---------------------------------------------------------------------------
__global__ __launch_bounds__(256) void merge_kernel(
    const short* __restrict__ pb0, const short* __restrict__ pb1,
    const float* __restrict__ lb0, const float* __restrict__ lb1,
    const int* __restrict__ maskp, short* __restrict__ ob) {
  int idx = blockIdx.x * 256 + threadIdx.x;  // 8192*64 threads
  int m = idx >> 6, e = (idx & 63) * 8;
  if (!maskp[m]) return;                     // masked row: flash wrote V
  int b = m >> 11, s = m & (S_ - 1);
  int bh = b * 8 + (e >> 6);
  float l = lb0[bh * S_ + s] + lb1[bh * S_ + s];
  float inv = 1.f / l;
  bf16x8 p0 = *(const bf16x8*)&pb0[(size_t)m * E_ + e];
  bf16x8 p1 = *(const bf16x8*)&pb1[(size_t)m * E_ + e];
  bf16x8 r;
  for (int j = 0; j < 8; ++j)
    r[j] = f2bf((bf2f(p0[j]) + bf2f(p1[j])) * inv);
  *(bf16x8*)&ob[(size_t)m * E_ + e] = r;
}

extern "C" void kernel_launch(void* const* d_in, const int* in_sizes, int n_in,
                              void* d_out, int out_size, void* d_ws, size_t ws_size,
                              hipStream_t stream) {
  const float* x    = (const float*)d_in[0];
  const int*   mask = (const int*)d_in[1];
  const float* Win  = (const float*)d_in[2];
  const float* Wout = (const float*)d_in[3];
  float* out = (float*)d_out;

  short* Xb    = (short*)d_ws;               // 8192*512
  short* Winb  = Xb + 8192 * 512;            // 1536*512
  short* Woutb = Winb + 1536 * 512;          // 512*512
  short* qb    = Woutb + 512 * 512;          // 32*2048*64 each
  short* kb    = qb + 32 * 2048 * 64;
  short* vbT   = kb + 32 * 2048 * 64;        // [bh][d][s] transposed
  short* ob    = vbT + 32 * 2048 * 64;       // 8192*512
  short* pb0   = ob + 8192 * 512;            // partial O, half 0 (bf16)
  short* pb1   = pb0 + 8192 * 512;           // partial O, half 1
  float* lb0   = (float*)(pb1 + 8192 * 512); // lsum partials [32][2048]
  float* lb1   = lb0 + 32 * 2048;            // total ws ~61.3 MB
  float* tab   = (float*)ob;                 // RoPE table (256KB) in ob
                                             // region — dead until flash

  cvt_all<<<5248, 256, 0, stream>>>(x, Win, Wout, Xb, Winb, Woutb, tab);
  gemm_qkv_mfma<<<dim3(64, 24), 256, 0, stream>>>(Xb, Winb, tab, qb, kb, vbT);
  flash_mfma<<<1024, 256, 0, stream>>>(qb, kb, vbT, mask, pb0, pb1, lb0, lb1, ob);
  merge_kernel<<<2048, 256, 0, stream>>>(pb0, pb1, lb0, lb1, mask, ob);
  gemm_out_mfma<<<dim3(64, 8), 256, 0, stream>>>(ob, Woutb, out);
}

// Round 20
// 157.938 us; speedup vs baseline: 1.0101x; 1.0027x over previous
//
#include <hip/hip_runtime.h>
#include <math.h>

// Problem constants
#define B_ 4
#define S_ 2048
#define E_ 512
#define H_ 8
#define D_ 64

typedef short bf16x8 __attribute__((ext_vector_type(8)));
typedef float f32x4 __attribute__((ext_vector_type(4)));

__device__ inline short f2bf(float f) {  // fp32 -> bf16 bits, RNE
  union { float f; unsigned u; } v; v.f = f;
  unsigned r = v.u + 0x7FFF + ((v.u >> 16) & 1);
  return (short)(r >> 16);
}
__device__ inline short f2bf_fast(float f) {  // round-half-up (P matrix only)
  union { float f; unsigned u; } v; v.f = f;
  return (short)((v.u + 0x8000u) >> 16);
}
__device__ inline float bf2f(short s) {
  union { unsigned u; float f; } v; v.u = ((unsigned)(unsigned short)s) << 16;
  return v.f;
}
// raw v_exp_f32: 2^x in one instruction (verified correct r5-r19).
__device__ __forceinline__ float exp2_hw(float x) {
  float r; asm("v_exp_f32 %0, %1" : "=v"(r) : "v"(x)); return r;
}

// Async global->LDS, 16B per lane (GEMM staging only).
__device__ __forceinline__ void gload16(const short* g, short* l) {
  __builtin_amdgcn_global_load_lds(
      (__attribute__((address_space(1))) void*)g,
      (__attribute__((address_space(3))) void*)l, 16, 0, 0);
}

// ---------------------------------------------------------------------------
// fused fp32->bf16 convert for X, W_in, W_out + RoPE cos/sin table
// (2048 x 16 float2, 256 KB) built into the ob region — dead during
// gemm_qkv, overwritten later by flash/merge. (r16 WIN: -1.3us)
// ---------------------------------------------------------------------------
__global__ __launch_bounds__(256) void cvt_all(
    const float* __restrict__ x, const float* __restrict__ win,
    const float* __restrict__ wout, short* __restrict__ xb,
    short* __restrict__ winb, short* __restrict__ woutb,
    float* __restrict__ tab) {
  int bid = blockIdx.x;
  if (bid >= 5120) {                         // RoPE table: idx = s*16 + dd
    int idx = (bid - 5120) * 256 + threadIdx.x;   // [0, 32768)
    int s = idx >> 4, dd = idx & 15;
    float fr = exp2f((float)dd * -0.8304820237f); // theta^(-2dd/32)
    float sn, cs;
    sincosf((float)s * fr, &sn, &cs);
    ((float2*)tab)[idx] = make_float2(cs, sn);
    return;
  }
  const float* src; short* dst; int i;
  if (bid < 4096)      { src = x;    dst = xb;    i = bid * 256 + threadIdx.x; }
  else if (bid < 4864) { src = win;  dst = winb;  i = (bid - 4096) * 256 + threadIdx.x; }
  else                 { src = wout; dst = woutb; i = (bid - 4864) * 256 + threadIdx.x; }
  float4 f = ((const float4*)src)[i];
  short4 o;
  o.x = f2bf(f.x); o.y = f2bf(f.y); o.z = f2bf(f.z); o.w = f2bf(f.w);
  ((short4*)dst)[i] = o;
}

// ---------------------------------------------------------------------------
// MFMA GEMM qkv (FROZEN: r4 structure + r15 setprio + r16 table-RoPE):
// 128x64 tile, BK=32, 4 waves, async global_load_lds staging, LDS dbuf,
// ONE barrier/K-step, 1536 blocks = 6/CU. Epilogue RoPE via L2-resident
// float2 table. q,k [bh][s][d]; V TRANSPOSED [bh][d][s].
// ---------------------------------------------------------------------------
__global__ __launch_bounds__(256, 6) void gemm_qkv_mfma(
    const short* __restrict__ Xb,    // [8192][512] bf16
    const short* __restrict__ Wb,    // [1536][512] bf16
    const float* __restrict__ tab,   // [2048][16] float2 cos/sin
    short* __restrict__ qb, short* __restrict__ kb, short* __restrict__ vbT) {
  __shared__ __align__(16) short As[2 * 128 * 32];   // 16 KB
  __shared__ __align__(16) short Bs[2 * 64 * 32];    //  8 KB
  const int tid = threadIdx.x;
  const int w = tid >> 6, lane = tid & 63;
  const int l15 = lane & 15, quad = lane >> 4;
  const int wm = w & 1, wn = w >> 1;
  const int m0 = blockIdx.x * 128;
  const int n0 = blockIdx.y * 64;

  const int srow = tid >> 2, sch = (tid & 3) * 8;
  const short* gA0 = Xb + (size_t)(m0 + srow) * E_ + sch;
  const short* gA1 = Xb + (size_t)(m0 + srow + 64) * E_ + sch;
  const short* gB0 = Wb + (size_t)(n0 + srow) * E_ + sch;

  f32x4 acc[4][2];
  for (int mt = 0; mt < 4; ++mt)
    for (int nt = 0; nt < 2; ++nt) acc[mt][nt] = (f32x4){0.f, 0.f, 0.f, 0.f};

  gload16(gA0, &As[tid * 8]);
  gload16(gA1, &As[2048 + tid * 8]);
  gload16(gB0, &Bs[tid * 8]);
  gA0 += 32; gA1 += 32; gB0 += 32;
  __syncthreads();

  int cur = 0;
  for (int t = 0; t < 16; ++t) {
    if (t < 15) {
      const int nbA = (cur ^ 1) * 4096, nbB = (cur ^ 1) * 2048;
      gload16(gA0, &As[nbA + tid * 8]);
      gload16(gA1, &As[nbA + 2048 + tid * 8]);
      gload16(gB0, &Bs[nbB + tid * 8]);
      gA0 += 32; gA1 += 32; gB0 += 32;
    }
    const int cbA = cur * 4096, cbB = cur * 2048;
    bf16x8 a[4], bfr[2];
#pragma unroll
    for (int mt = 0; mt < 4; ++mt)
      a[mt] = *(const bf16x8*)&As[cbA + (wm * 64 + mt * 16 + l15) * 32 + quad * 8];
#pragma unroll
    for (int nt = 0; nt < 2; ++nt)
      bfr[nt] = *(const bf16x8*)&Bs[cbB + (wn * 32 + nt * 16 + l15) * 32 + quad * 8];
    __builtin_amdgcn_s_setprio(1);           // T5 (r15, neutral-kept)
#pragma unroll
    for (int mt = 0; mt < 4; ++mt)
#pragma unroll
      for (int nt = 0; nt < 2; ++nt)
        acc[mt][nt] = __builtin_amdgcn_mfma_f32_16x16x32_bf16(a[mt], bfr[nt], acc[mt][nt], 0, 0, 0);
    __builtin_amdgcn_s_setprio(0);
    __syncthreads();
    cur ^= 1;
  }

  const int t3 = n0 >> 9;                // uniform per block: 0=q 1=k 2=v
  for (int nt = 0; nt < 2; ++nt) {
    const int n = n0 + wn * 32 + nt * 16 + l15;
    const int h = (n >> 6) & 7;
    const int d = n & 63;
    const bool dorope = (t3 < 2) && (d < 32);
    const float sgn = (d & 1) ? 1.f : -1.f;
    const int dd = d >> 1;                 // valid only under dorope
    for (int mt = 0; mt < 4; ++mt) {
      for (int i = 0; i < 4; ++i) {
        const int m = m0 + wm * 64 + mt * 16 + quad * 4 + i;
        const int b = m >> 11, s = m & (S_ - 1);
        float val = acc[mt][nt][i];
        float pv = __shfl_xor(val, 1, 64);
        float outv = val;
        if (dorope) {
          float2 cs = ((const float2*)tab)[(s << 4) | dd];
          outv = val * cs.x + pv * sgn * cs.y;
        }
        if (t3 == 2)
          vbT[((size_t)(b * 8 + h) * D_ + d) * S_ + s] = f2bf(outv);
        else {
          short* dst = (t3 == 0) ? qb : kb;
          dst[(((size_t)(b * 8 + h)) * S_ + s) * D_ + d] = f2bf(outv);
        }
      }
    }
  }
}

// ---------------------------------------------------------------------------
// gemm_out (FROZEN: r14 BK=64 structure + r15 setprio). 2 blocks/CU grid-
// capped; 8 iters x 8 barriers, 32 MFMA/barrier, two conflict-free [*][32]
// sub-tiles, LDS 48 KB (free at this residency).
// ---------------------------------------------------------------------------
__global__ __launch_bounds__(256) void gemm_out_mfma(
    const short* __restrict__ Ab, const short* __restrict__ Wb,
    float* __restrict__ out) {
  __shared__ __align__(16) short As[2 * 2 * 128 * 32];   // 32 KB
  __shared__ __align__(16) short Bs[2 * 2 * 64 * 32];    // 16 KB
  const int tid = threadIdx.x;
  const int w = tid >> 6, lane = tid & 63;
  const int l15 = lane & 15, quad = lane >> 4;
  const int wm = w & 1, wn = w >> 1;
  const int m0 = blockIdx.x * 128;
  const int n0 = blockIdx.y * 64;

  const int srow = tid >> 2, sch = (tid & 3) * 8;
  const short* gA0 = Ab + (size_t)(m0 + srow) * E_ + sch;        // rows 0-63
  const short* gA1 = Ab + (size_t)(m0 + srow + 64) * E_ + sch;   // rows 64-127
  const short* gB0 = Wb + (size_t)(n0 + srow) * E_ + sch;        // rows 0-63

  f32x4 acc[4][2];
  for (int mt = 0; mt < 4; ++mt)
    for (int nt = 0; nt < 2; ++nt) acc[mt][nt] = (f32x4){0.f, 0.f, 0.f, 0.f};

#define STAGE_OUT(buf, koff)                                         \
  {                                                                  \
    const int ab = (buf) * 8192, bb = (buf) * 4096;                  \
    gload16(gA0 + (koff),      &As[ab + tid * 8]);                   \
    gload16(gA1 + (koff),      &As[ab + 2048 + tid * 8]);            \
    gload16(gA0 + (koff) + 32, &As[ab + 4096 + tid * 8]);            \
    gload16(gA1 + (koff) + 32, &As[ab + 4096 + 2048 + tid * 8]);     \
    gload16(gB0 + (koff),      &Bs[bb + tid * 8]);                   \
    gload16(gB0 + (koff) + 32, &Bs[bb + 2048 + tid * 8]);            \
  }

  STAGE_OUT(0, 0);
  __syncthreads();

  int cur = 0;
  for (int t = 0; t < 8; ++t) {
    if (t < 7) STAGE_OUT(cur ^ 1, (t + 1) * 64);
    const int cbA = cur * 8192, cbB = cur * 4096;
#pragma unroll
    for (int s = 0; s < 2; ++s) {
      bf16x8 a[4], bfr[2];
#pragma unroll
      for (int mt = 0; mt < 4; ++mt)
        a[mt] = *(const bf16x8*)&As[cbA + s * 4096 + (wm * 64 + mt * 16 + l15) * 32 + quad * 8];
#pragma unroll
      for (int nt = 0; nt < 2; ++nt)
        bfr[nt] = *(const bf16x8*)&Bs[cbB + s * 2048 + (wn * 32 + nt * 16 + l15) * 32 + quad * 8];
      __builtin_amdgcn_s_setprio(1);
#pragma unroll
      for (int mt = 0; mt < 4; ++mt)
#pragma unroll
        for (int nt = 0; nt < 2; ++nt)
          acc[mt][nt] = __builtin_amdgcn_mfma_f32_16x16x32_bf16(a[mt], bfr[nt], acc[mt][nt], 0, 0, 0);
      __builtin_amdgcn_s_setprio(0);
    }
    __syncthreads();
    cur ^= 1;
  }
#undef STAGE_OUT
  for (int mt = 0; mt < 4; ++mt)
    for (int nt = 0; nt < 2; ++nt) {
      const int n = n0 + wn * 32 + nt * 16 + l15;
      for (int i = 0; i < 4; ++i) {
        const int m = m0 + wm * 64 + mt * 16 + quad * 4 + i;
        out[(size_t)m * E_ + n] = acc[mt][nt][i];
      }
    }
}

// ---------------------------------------------------------------------------
// Flash attention (FROZEN at r13 = r6 structure + T5 setprio; band
// 46.1-48.8 across identical-binary runs). grid 1024 balanced pairs,
// stride 72, staged K/V loop, kbias LDS, 2 barriers/tile, exp2_hw, setprio
// around MFMA clusters. Refuted: stride-68 (+4), T14 (+7), grid-2048
// (+3.5), direct-global frags (2.6x). The path past ~47us is the full
// 8-warp 32x32 dep-graph rewrite — partial grafts all measured negative.
// ---------------------------------------------------------------------------
__global__ __launch_bounds__(256) void flash_mfma(
    const short* __restrict__ qb, const short* __restrict__ kb,
    const short* __restrict__ vbT, const int* __restrict__ maskp,
    short* __restrict__ pb0, short* __restrict__ pb1,
    float* __restrict__ lb0, float* __restrict__ lb1,
    short* __restrict__ ob) {
  __shared__ __align__(16) short Ks[64][72];
  __shared__ __align__(16) short VT[64][72];
  __shared__ __align__(16) short Pl[4][16][72];
  __shared__ float kbias[64];
  const int tid = threadIdx.x;
  const int w = tid >> 6, lane = tid & 63;
  const int l15 = lane & 15, quad = lane >> 4;
  const int bid = blockIdx.x;
  const int u = bid & 7, v = bid >> 3;       // u -> XCD under id&7 model
  const int bh = (u << 2) | (v & 3);         // 4 bh per XCD
  const int w2 = v >> 2;                     // 0..31
  const int pair = w2 & 15;                  // q-tile pair id
  const int kh = w2 >> 4;                    // split half: 0 or 1
  const int b = bh >> 3, hd = bh & 7;
  const short* qbase = qb + (size_t)bh * S_ * D_;
  const short* kbase = kb + (size_t)bh * S_ * D_;
  const short* vtb   = vbT + (size_t)bh * D_ * S_;
  short* PB = kh ? pb1 : pb0;
  float* LB = kh ? lb1 : lb0;
  const float c2 = 0.1803368801f;            // 0.125 * log2(e)
  bf16x8 ones;
  for (int j = 0; j < 8; ++j) ones[j] = (short)0x3F80;  // bf16 1.0

  for (int seg = 0; seg < 2; ++seg) {
    const int qt = (seg == 0) ? pair : 31 - pair;
    const int r0 = qt * 64;
    const int mid = (qt + 2) >> 1;           // ceil((qt+1)/2)
    const int lo = kh ? mid : 0;
    const int hi = kh ? (qt + 1) : mid;
    bf16x8 aq[2];
    {
      const short* qrow = qbase + (size_t)(r0 + 16 * w + l15) * D_;
      aq[0] = *(const bf16x8*)&qrow[quad * 8];
      aq[1] = *(const bf16x8*)&qrow[32 + quad * 8];
    }
    f32x4 o[4], lsum;
    for (int no = 0; no < 4; ++no) o[no] = (f32x4){0.f, 0.f, 0.f, 0.f};
    lsum = (f32x4){0.f, 0.f, 0.f, 0.f};

    for (int kt = lo; kt < hi; ++kt) {
      const int t0 = kt * 64;
      __syncthreads();                       // prior tile fully consumed
      for (int l = 0; l < 2; ++l) {
        int idx = tid + 256 * l;
        int row = idx >> 3, ch = (idx & 7) * 8;
        *(bf16x8*)&Ks[row][ch] = *(const bf16x8*)(kbase + (size_t)(t0 + row) * D_ + ch);
        *(bf16x8*)&VT[row][ch] = *(const bf16x8*)(vtb + (size_t)row * S_ + t0 + ch);
      }
      if (tid < 64)
        kbias[tid] = maskp[b * S_ + t0 + tid] ? -23.08312f : -1.0e38f;
      __syncthreads();
      f32x4 sfr[4];
      for (int nb = 0; nb < 4; ++nb) sfr[nb] = (f32x4){0.f, 0.f, 0.f, 0.f};
      __builtin_amdgcn_s_setprio(1);         // T5: favor MFMA cluster
      for (int nb = 0; nb < 4; ++nb)
        for (int ks = 0; ks < 2; ++ks) {
          bf16x8 bk = *(const bf16x8*)&Ks[l15 + 16 * nb][32 * ks + quad * 8];
          sfr[nb] = __builtin_amdgcn_mfma_f32_16x16x32_bf16(aq[ks], bk, sfr[nb], 0, 0, 0);
        }
      __builtin_amdgcn_s_setprio(0);
      if (kt < qt) {                         // interior tiles: no causal test
        for (int nb = 0; nb < 4; ++nb) {
          const float bb = kbias[l15 + 16 * nb];
          for (int i = 0; i < 4; ++i)
            Pl[w][quad * 4 + i][l15 + 16 * nb] = f2bf_fast(exp2_hw(sfr[nb][i] * c2 + bb));
        }
      } else {                               // boundary tile: add causal mask
        for (int nb = 0; nb < 4; ++nb) {
          const int tg = l15 + 16 * nb;
          const float bb = kbias[l15 + 16 * nb];
          for (int i = 0; i < 4; ++i) {
            const float bbi = (tg > 16 * w + quad * 4 + i) ? -1.0e38f : bb;
            Pl[w][quad * 4 + i][l15 + 16 * nb] = f2bf_fast(exp2_hw(sfr[nb][i] * c2 + bbi));
          }
        }
      }
      asm volatile("s_waitcnt lgkmcnt(0)" ::: "memory");  // own-wave Pl writes
      bf16x8 ap0 = *(const bf16x8*)&Pl[w][l15][quad * 8];
      bf16x8 ap1 = *(const bf16x8*)&Pl[w][l15][32 + quad * 8];
      __builtin_amdgcn_s_setprio(1);         // T5: favor PV cluster
      for (int no = 0; no < 4; ++no) {
        bf16x8 bv0 = *(const bf16x8*)&VT[16 * no + l15][quad * 8];
        bf16x8 bv1 = *(const bf16x8*)&VT[16 * no + l15][32 + quad * 8];
        o[no] = __builtin_amdgcn_mfma_f32_16x16x32_bf16(ap0, bv0, o[no], 0, 0, 0);
        o[no] = __builtin_amdgcn_mfma_f32_16x16x32_bf16(ap1, bv1, o[no], 0, 0, 0);
      }
      lsum = __builtin_amdgcn_mfma_f32_16x16x32_bf16(ap0, ones, lsum, 0, 0, 0);
      lsum = __builtin_amdgcn_mfma_f32_16x16x32_bf16(ap1, ones, lsum, 0, 0, 0);
      __builtin_amdgcn_s_setprio(0);
    }
    // epilogue: write partials; kh=0 also writes V rows for masked queries
    for (int i = 0; i < 4; ++i) {
      const int s = r0 + 16 * w + quad * 4 + i;
      const int qm = maskp[b * S_ + s];
      const size_t row = (size_t)(b * S_ + s) * E_ + hd * D_;
      if (kh == 0 && !qm) {
        for (int no = 0; no < 4; ++no) {
          const int d = l15 + 16 * no;
          ob[row + d] = vtb[(size_t)d * S_ + s];
        }
      }
      for (int no = 0; no < 4; ++no)
        PB[row + l15 + 16 * no] = f2bf(o[no][i]);
      if (l15 == 0)
        LB[bh * S_ + s] = lsum[i];
    }
  }
}

// ---------------------------------------------------------------------------
// merge: ob[m][e] = (P0 + P1) / (l0 + l1) for unmasked rows
// ---------------------------------------------------------------------------
__global__ __launch_bounds__(256) void merge_kernel(
    const short* __restrict__ pb0, const short* __restrict__ pb1,
    const float* __restrict__ lb0, const float* __restrict__ lb1,
    const int* __restrict__ maskp, short* __restrict__ ob) {
  int idx = blockIdx.x * 256 + threadIdx.x;  // 8192*64 threads
  int m = idx >> 6, e = (idx & 63) * 8;
  if (!maskp[m]) return;                     // masked row: flash wrote V
  int b = m >> 11, s = m & (S_ - 1);
  int bh = b * 8 + (e >> 6);
  float l = lb0[bh * S_ + s] + lb1[bh * S_ + s];
  float inv = 1.f / l;
  bf16x8 p0 = *(const bf16x8*)&pb0[(size_t)m * E_ + e];
  bf16x8 p1 = *(const bf16x8*)&pb1[(size_t)m * E_ + e];
  bf16x8 r;
  for (int j = 0; j < 8; ++j)
    r[j] = f2bf((bf2f(p0[j]) + bf2f(p1[j])) * inv);
  *(bf16x8*)&ob[(size_t)m * E_ + e] = r;
}

extern "C" void kernel_launch(void* const* d_in, const int* in_sizes, int n_in,
                              void* d_out, int out_size, void* d_ws, size_t ws_size,
                              hipStream_t stream) {
  const float* x    = (const float*)d_in[0];
  const int*   mask = (const int*)d_in[1];
  const float* Win  = (const float*)d_in[2];
  const float* Wout = (const float*)d_in[3];
  float* out = (float*)d_out;

  short* Xb    = (short*)d_ws;               // 8192*512
  short* Winb  = Xb + 8192 * 512;            // 1536*512
  short* Woutb = Winb + 1536 * 512;          // 512*512
  short* qb    = Woutb + 512 * 512;          // 32*2048*64 each
  short* kb    = qb + 32 * 2048 * 64;
  short* vbT   = kb + 32 * 2048 * 64;        // [bh][d][s] transposed
  short* ob    = vbT + 32 * 2048 * 64;       // 8192*512
  short* pb0   = ob + 8192 * 512;            // partial O, half 0 (bf16)
  short* pb1   = pb0 + 8192 * 512;           // partial O, half 1
  float* lb0   = (float*)(pb1 + 8192 * 512); // lsum partials [32][2048]
  float* lb1   = lb0 + 32 * 2048;            // total ws ~61.3 MB
  float* tab   = (float*)ob;                 // RoPE table (256KB) in ob
                                             // region — dead until flash

  cvt_all<<<5248, 256, 0, stream>>>(x, Win, Wout, Xb, Winb, Woutb, tab);
  gemm_qkv_mfma<<<dim3(64, 24), 256, 0, stream>>>(Xb, Winb, tab, qb, kb, vbT);
  flash_mfma<<<1024, 256, 0, stream>>>(qb, kb, vbT, mask, pb0, pb1, lb0, lb1, ob);
  merge_kernel<<<2048, 256, 0, stream>>>(pb0, pb1, lb0, lb1, mask, ob);
  gemm_out_mfma<<<dim3(64, 8), 256, 0, stream>>>(ob, Woutb, out);
}